// Round 7
// baseline (643.267 us; speedup 1.0000x reference)
//
#include <hip/hip_runtime.h>

// MHA block for MI355X, v5.
// presplit(fp32->hi/lo fp16) ; gemm 2-phase LDS double-buffer (global_load_lds)
// ; flash attention v4: 4 waves/block share one head's K/V via XOR-swizzled LDS
// (reg-staged, T14 write-late), paired q-tiles (r,63-r), swapped QK^T,
// defer-max online softmax ; O-proj GEMM.

typedef _Float16 h8 __attribute__((ext_vector_type(8)));
typedef float f32x4 __attribute__((ext_vector_type(4)));
typedef float f32x16 __attribute__((ext_vector_type(16)));

#define S_LEN 2048
#define DM 1024
#define DK 64

struct H2 { _Float16 h, l; };
__device__ __forceinline__ H2 split2(float v) {
  H2 r; r.h = (_Float16)v; r.l = (_Float16)(v - (float)r.h); return r;
}
__device__ __forceinline__ unsigned int pack2(float a, float b) {
  union { _Float16 h[2]; unsigned int u; } x;
  x.h[0] = (_Float16)a; x.h[1] = (_Float16)b;
  return x.u;
}

#define GLOAD16(gp, lp)                                                        \
  __builtin_amdgcn_global_load_lds(                                            \
      (const __attribute__((address_space(1))) void*)(gp),                     \
      (__attribute__((address_space(3))) void*)(lp), 16, 0, 0)

// fp32 -> (hi, lo) fp16 planes, 8 elements/thread.
__global__ __launch_bounds__(256)
void presplit(const float* __restrict__ X, _Float16* __restrict__ Hi,
              _Float16* __restrict__ Lo, int n8) {
  const int i = blockIdx.x * 256 + threadIdx.x;
  if (i >= n8) return;
  const float4 a = ((const float4*)X)[2 * i];
  const float4 b = ((const float4*)X)[2 * i + 1];
  h8 hv, lv;
  H2 s;
  s = split2(a.x); hv[0] = s.h; lv[0] = s.l;
  s = split2(a.y); hv[1] = s.h; lv[1] = s.l;
  s = split2(a.z); hv[2] = s.h; lv[2] = s.l;
  s = split2(a.w); hv[3] = s.h; lv[3] = s.l;
  s = split2(b.x); hv[4] = s.h; lv[4] = s.l;
  s = split2(b.y); hv[5] = s.h; lv[5] = s.l;
  s = split2(b.z); hv[6] = s.h; lv[6] = s.l;
  s = split2(b.w); hv[7] = s.h; lv[7] = s.l;
  *(h8*)&Hi[(size_t)i * 8] = hv;
  *(h8*)&Lo[(size_t)i * 8] = lv;
}

// Y[8192,1024] = X @ W^T + bias, X/W pre-split hi/lo fp16.
// 128x128 tile, BK=32, 4 waves; 2-phase double-buffered global_load_lds.
template<int OUT_MODE>
__global__ __launch_bounds__(256)
void gemm_ps(const _Float16* __restrict__ Xhi, const _Float16* __restrict__ Xlo,
             const _Float16* __restrict__ Whi, const _Float16* __restrict__ Wlo,
             const float* __restrict__ bias,
             _Float16* __restrict__ Yhi, _Float16* __restrict__ Ylo,
             float* __restrict__ Yf) {
  __shared__ _Float16 lds[2][4][128 * 32];  // [buf][plane: Ah Al Bh Bl][tile]
  const int tid = threadIdx.x;
  const int m0 = blockIdx.x * 128, n0 = blockIdx.y * 128;
  const int wid = tid >> 6, lane = tid & 63;
  const int wm = (wid >> 1) * 64, wn = (wid & 1) * 64;
  const int l15 = lane & 15, lg = lane >> 4;
  const _Float16* gsrc = (wid == 0) ? Xhi : (wid == 1) ? Xlo : (wid == 2) ? Whi : Wlo;
  const int rbase = (wid < 2) ? m0 : n0;
  const int rowoff = lane >> 2, coloff = (lane & 3) * 8;
  f32x4 acc[4][4] = {};

  auto stage = [&](int buf, int kt) {
    const int k0 = kt * 32;
#pragma unroll
    for (int c = 0; c < 8; ++c) {
      GLOAD16(&gsrc[(size_t)(rbase + c * 16 + rowoff) * DM + k0 + coloff],
              &lds[buf][wid][c * 512]);
    }
  };

  stage(0, 0);
  __syncthreads();
  for (int kt = 0; kt < 32; ++kt) {
    const int buf = kt & 1;
    if (kt + 1 < 32) stage(buf ^ 1, kt + 1);
    h8 a_h[4], a_l[4], b_h[4], b_l[4];
#pragma unroll
    for (int i = 0; i < 4; ++i) {
      const int ra = (wm + i * 16 + l15) * 32 + lg * 8;
      const int rb = (wn + i * 16 + l15) * 32 + lg * 8;
      a_h[i] = *(const h8*)&lds[buf][0][ra];
      a_l[i] = *(const h8*)&lds[buf][1][ra];
      b_h[i] = *(const h8*)&lds[buf][2][rb];
      b_l[i] = *(const h8*)&lds[buf][3][rb];
    }
    __builtin_amdgcn_s_setprio(1);
#pragma unroll
    for (int mi = 0; mi < 4; ++mi)
#pragma unroll
      for (int ni = 0; ni < 4; ++ni) {
        acc[mi][ni] = __builtin_amdgcn_mfma_f32_16x16x32_f16(a_h[mi], b_h[ni], acc[mi][ni], 0, 0, 0);
        acc[mi][ni] = __builtin_amdgcn_mfma_f32_16x16x32_f16(a_h[mi], b_l[ni], acc[mi][ni], 0, 0, 0);
        acc[mi][ni] = __builtin_amdgcn_mfma_f32_16x16x32_f16(a_l[mi], b_h[ni], acc[mi][ni], 0, 0, 0);
      }
    __builtin_amdgcn_s_setprio(0);
    __syncthreads();
  }
#pragma unroll
  for (int mi = 0; mi < 4; ++mi)
#pragma unroll
    for (int ni = 0; ni < 4; ++ni)
#pragma unroll
      for (int j = 0; j < 4; ++j) {
        const int rg = m0 + wm + mi * 16 + lg * 4 + j;  // C/D: row=(lane>>4)*4+reg
        const int cg = n0 + wn + ni * 16 + l15;         // col=lane&15
        const float v = acc[mi][ni][j] + bias[cg];
        if constexpr (OUT_MODE == 0) {
          H2 s = split2(v);
          Yhi[(size_t)rg * DM + cg] = s.h;
          Ylo[(size_t)rg * DM + cg] = s.l;
        } else {
          Yf[(size_t)rg * DM + cg] = v;
        }
      }
}

// Vp [B*S, DM] f32 -> Vt hi/lo [bh][d(64)][s(2048)] fp16
__global__ __launch_bounds__(256)
void mha_vtrans(const float* __restrict__ Vp,
                _Float16* __restrict__ Vthi, _Float16* __restrict__ Vtlo) {
  __shared__ float tile[64 * 65];
  const int bh = blockIdx.y, s0 = blockIdx.x * 64;
  const int b = bh >> 4, h = bh & 15;
  const int t = threadIdx.x;
  const int row = t >> 2, cg = (t & 3) * 16;
  const size_t inbase = ((size_t)(b * S_LEN + s0 + row)) * DM + h * DK + cg;
#pragma unroll
  for (int i = 0; i < 4; ++i) {
    const float4 v = *(const float4*)&Vp[inbase + i * 4];
    tile[row * 65 + cg + i * 4 + 0] = v.x;
    tile[row * 65 + cg + i * 4 + 1] = v.y;
    tile[row * 65 + cg + i * 4 + 2] = v.z;
    tile[row * 65 + cg + i * 4 + 3] = v.w;
  }
  __syncthreads();
  const int drow = t >> 2, sg = (t & 3) * 16;
  h8 hv0, hv1, lv0, lv1;
#pragma unroll
  for (int i = 0; i < 8; ++i) {
    H2 a = split2(tile[(sg + i) * 65 + drow]);
    hv0[i] = a.h; lv0[i] = a.l;
    H2 c = split2(tile[(sg + 8 + i) * 65 + drow]);
    hv1[i] = c.h; lv1[i] = c.l;
  }
  const size_t ob = ((size_t)bh * DK + drow) * S_LEN + s0 + sg;
  *(h8*)&Vthi[ob] = hv0;
  *(h8*)&Vthi[ob + 8] = hv1;
  *(h8*)&Vtlo[ob] = lv0;
  *(h8*)&Vtlo[ob + 8] = lv1;
}

// Flash attention v4: 4 waves/block, same head, pairs (4pg+w, 63-4pg-w).
// K/V staged once per block into XOR-swizzled LDS (reg-staged, write-late
// between barriers); QK^T swapped; defer-max softmax; PV from LDS V-tiles.
__global__ __launch_bounds__(256)
void mha_attn(const _Float16* __restrict__ Qhi, const _Float16* __restrict__ Qlo,
              const _Float16* __restrict__ Khi, const _Float16* __restrict__ Klo,
              const _Float16* __restrict__ Vthi, const _Float16* __restrict__ Vtlo,
              _Float16* __restrict__ Ohi, _Float16* __restrict__ Olo) {
  __shared__ int4 smem4[2080];  // 33280 B: K 2x8KB | V 2x8KB ; epilogue reuse
  char* smem = (char*)smem4;
  const int tid = threadIdx.x;
  const int w = tid >> 6, lane = tid & 63;
  const int l31 = lane & 31, hi = lane >> 5;
  // chunked XCD swizzle: XCD x -> heads [8x, 8x+8)
  const int hwid = blockIdx.x + (blockIdx.y << 3);        // grid (8, 64)
  const int logical = (hwid & 7) * 64 + (hwid >> 3);
  const int bh = logical >> 3, pg = logical & 7;
  const int r = pg * 4 + w;                                // near q-tile
  const int fq = 63 - r;                                   // far q-tile
  const int TMAX = 63 - pg * 4;                            // block loop bound
  const int b = bh >> 4, h = bh & 15;
  const size_t rowbase = (size_t)b * S_LEN * DM + h * DK;
  const size_t vbase = (size_t)bh * DK * S_LEN;

  // staging roles (block-wide)
  const int krow = tid >> 3, kq = tid & 7;   // K: row 0..31, slots kq / kq+8
  const int vd = tid >> 2, vj = tid & 3;     // V: d 0..63, slots vj / vj+4

  auto kaddr = [&](int buf, int row, int slot) {
    return buf * 8192 + row * 256 + ((slot ^ (row & 15)) << 4);
  };
  auto vaddr = [&](int buf, int d, int slot) {
    return 16384 + buf * 8192 + d * 128 + ((slot ^ (d & 7)) << 4);
  };

  h8 sKh, sKl, sVh, sVl;  // staged regs (global -> reg -> LDS)
  auto stage_load = [&](int t) {
    const int c0 = t * 32;
    const size_t ko = rowbase + (size_t)(c0 + krow) * DM + kq * 8;
    const size_t vo = vbase + (size_t)vd * S_LEN + c0 + vj * 8;
    sKh = *(const h8*)&Khi[ko];
    sKl = *(const h8*)&Klo[ko];
    sVh = *(const h8*)&Vthi[vo];
    sVl = *(const h8*)&Vtlo[vo];
  };
  auto stage_write = [&](int buf) {
    *(h8*)(smem + kaddr(buf, krow, kq)) = sKh;
    *(h8*)(smem + kaddr(buf, krow, kq + 8)) = sKl;
    *(h8*)(smem + vaddr(buf, vd, vj)) = sVh;
    *(h8*)(smem + vaddr(buf, vd, vj + 4)) = sVl;
  };

  stage_load(0);
  // Q fragments (issued after stage(0) loads; latency overlaps prologue)
  h8 qh_r[4], ql_r[4], qh_f[4], ql_f[4];
#pragma unroll
  for (int ks = 0; ks < 4; ++ks) {
    const size_t offr = rowbase + (size_t)(r * 32 + l31) * DM + ks * 16 + hi * 8;
    const size_t offf = rowbase + (size_t)(fq * 32 + l31) * DM + ks * 16 + hi * 8;
    qh_r[ks] = *(const h8*)&Qhi[offr]; ql_r[ks] = *(const h8*)&Qlo[offr];
    qh_f[ks] = *(const h8*)&Qhi[offf]; ql_f[ks] = *(const h8*)&Qlo[offf];
  }
  stage_write(0);
  __syncthreads();

  f32x16 po0r = {}, po1r = {}, po0f = {}, po1f = {};
  float m_r = -1e30f, l_r = 0.0f, m_f = -1e30f, l_f = 0.0f;

  auto smax_pv = [&](int buf, const f32x16& sA, const f32x16& sB, bool diag,
                     float& m, float& l, f32x16& po0, f32x16& po1) {
    float p[16];
    float tmax = -3e38f;
#pragma unroll
    for (int rr = 0; rr < 16; ++rr) {
      const int kvr = (rr & 3) + 8 * (rr >> 2) + 4 * hi;  // C/D row map (measured)
      float sv = (sA[rr] + sB[rr]) * 0.125f;              // 1/sqrt(64)
      if (diag && kvr > l31) sv = -1e30f;                 // causal mask
      p[rr] = sv;
      tmax = fmaxf(tmax, sv);
    }
    tmax = fmaxf(tmax, __shfl_xor(tmax, 32, 64));
    if (!__all(tmax <= m + 8.0f)) {  // defer-max (T13)
      const float mnew = fmaxf(m, tmax);
      const float alpha = __expf(m - mnew);
      l *= alpha;
      po0 = po0 * alpha;
      po1 = po1 * alpha;
      m = mnew;
    }
    float tsum = 0.0f;
#pragma unroll
    for (int rr = 0; rr < 16; ++rr) { p[rr] = __expf(p[rr] - m); tsum += p[rr]; }
    tsum += __shfl_xor(tsum, 32, 64);
    l += tsum;
    unsigned int pw[8], qw[8];
#pragma unroll
    for (int g = 0; g < 8; ++g) pw[g] = pack2(p[2 * g], p[2 * g + 1]);
#pragma unroll
    for (int g = 0; g < 8; ++g) qw[g] = (unsigned int)__shfl_xor((int)pw[g], 32, 64);
    __builtin_amdgcn_s_setprio(1);
#pragma unroll
    for (int cks = 0; cks < 2; ++cks) {
      union { unsigned int u[4]; h8 v; } bp;
      if (hi == 0) {
        bp.u[0] = pw[4 * cks];     bp.u[1] = pw[4 * cks + 1];
        bp.u[2] = qw[4 * cks];     bp.u[3] = qw[4 * cks + 1];
      } else {
        bp.u[0] = qw[4 * cks + 2]; bp.u[1] = qw[4 * cks + 3];
        bp.u[2] = pw[4 * cks + 2]; bp.u[3] = pw[4 * cks + 3];
      }
      const h8 vh0 = *(const h8*)(smem + vaddr(buf, l31, 2 * cks + hi));
      const h8 vl0 = *(const h8*)(smem + vaddr(buf, l31, 4 + 2 * cks + hi));
      const h8 vh1 = *(const h8*)(smem + vaddr(buf, l31 + 32, 2 * cks + hi));
      const h8 vl1 = *(const h8*)(smem + vaddr(buf, l31 + 32, 4 + 2 * cks + hi));
      po0 = __builtin_amdgcn_mfma_f32_32x32x16_f16(vh0, bp.v, po0, 0, 0, 0);
      po0 = __builtin_amdgcn_mfma_f32_32x32x16_f16(vl0, bp.v, po0, 0, 0, 0);
      po1 = __builtin_amdgcn_mfma_f32_32x32x16_f16(vh1, bp.v, po1, 0, 0, 0);
      po1 = __builtin_amdgcn_mfma_f32_32x32x16_f16(vl1, bp.v, po1, 0, 0, 0);
    }
    __builtin_amdgcn_s_setprio(0);
  };

  for (int t = 0; t <= TMAX; ++t) {
    const int buf = t & 1;
    if (t < TMAX) stage_load(t + 1);  // issue-early: latency hides under compute
    if (t <= fq) {
      h8 kh[4], kl[4];
#pragma unroll
      for (int ks = 0; ks < 4; ++ks) {
        kh[ks] = *(const h8*)(smem + kaddr(buf, l31, 2 * ks + hi));
        kl[ks] = *(const h8*)(smem + kaddr(buf, l31, 8 + 2 * ks + hi));
      }
      {  // far q-tile
        f32x16 sA = {}, sB = {};
        __builtin_amdgcn_s_setprio(1);
#pragma unroll
        for (int ks = 0; ks < 4; ++ks) {
          sA = __builtin_amdgcn_mfma_f32_32x32x16_f16(kh[ks], qh_f[ks], sA, 0, 0, 0);
          sB = __builtin_amdgcn_mfma_f32_32x32x16_f16(kh[ks], ql_f[ks], sB, 0, 0, 0);
          sB = __builtin_amdgcn_mfma_f32_32x32x16_f16(kl[ks], qh_f[ks], sB, 0, 0, 0);
        }
        __builtin_amdgcn_s_setprio(0);
        smax_pv(buf, sA, sB, t == fq, m_f, l_f, po0f, po1f);
      }
      if (t <= r) {  // near q-tile
        f32x16 sA = {}, sB = {};
        __builtin_amdgcn_s_setprio(1);
#pragma unroll
        for (int ks = 0; ks < 4; ++ks) {
          sA = __builtin_amdgcn_mfma_f32_32x32x16_f16(kh[ks], qh_r[ks], sA, 0, 0, 0);
          sB = __builtin_amdgcn_mfma_f32_32x32x16_f16(kh[ks], ql_r[ks], sB, 0, 0, 0);
          sB = __builtin_amdgcn_mfma_f32_32x32x16_f16(kl[ks], qh_r[ks], sB, 0, 0, 0);
        }
        __builtin_amdgcn_s_setprio(0);
        smax_pv(buf, sA, sB, t == r, m_r, l_r, po0r, po1r);
      }
    }
    __syncthreads();                       // BAR1: all reads of buf done
    if (t < TMAX) stage_write(buf ^ 1);    // write-late (T14)
    __syncthreads();                       // BAR2: writes visible
  }

  // epilogue: per-wave LDS transpose region (no cross-wave aliasing)
  unsigned int* outl = (unsigned int*)(smem + w * 8320);
  auto writeO = [&](int qt, float l, const f32x16& po0, const f32x16& po1) {
    const float invl = 1.0f / l;
#pragma unroll
    for (int rr = 0; rr < 16; ++rr) {
      const int dl = (rr & 3) + 8 * (rr >> 2) + 4 * hi;
      H2 s0 = split2(po0[rr] * invl);
      H2 s1 = split2(po1[rr] * invl);
      union { _Float16 f[2]; unsigned int u; } x0, x1;
      x0.f[0] = s0.h; x0.f[1] = s0.l;
      x1.f[0] = s1.h; x1.f[1] = s1.l;
      outl[l31 * 65 + dl] = x0.u;
      outl[l31 * 65 + 32 + dl] = x1.u;
    }
    const size_t ob = ((size_t)b * S_LEN + qt * 32) * DM + h * DK;
    for (int r2 = 0; r2 < 32; ++r2) {
      union { unsigned int u; _Float16 f[2]; } x;
      x.u = outl[r2 * 65 + lane];
      Ohi[ob + (size_t)r2 * DM + lane] = x.f[0];
      Olo[ob + (size_t)r2 * DM + lane] = x.f[1];
    }
  };
  writeO(fq, l_f, po0f, po1f);
  writeO(r, l_r, po0r, po1r);
}

extern "C" void kernel_launch(void* const* d_in, const int* in_sizes, int n_in,
                              void* d_out, int out_size, void* d_ws, size_t ws_size,
                              hipStream_t stream) {
  const float* q   = (const float*)d_in[0];
  const float* k   = (const float*)d_in[1];
  const float* v   = (const float*)d_in[2];
  // d_in[3] = causal mask, implemented analytically
  const float* w_q = (const float*)d_in[4];
  const float* b_q = (const float*)d_in[5];
  const float* w_k = (const float*)d_in[6];
  const float* b_k = (const float*)d_in[7];
  const float* w_v = (const float*)d_in[8];
  const float* b_v = (const float*)d_in[9];
  const float* w_o = (const float*)d_in[10];
  const float* b_o = (const float*)d_in[11];

  const size_t NIN = (size_t)8192 * 1024;      // input/activation elements
  const size_t NW  = (size_t)1024 * 1024;      // weight elements
  const size_t SZH = NIN * sizeof(_Float16);   // 16.78 MB
  char* ws = (char*)d_ws;
  _Float16* b1 = (_Float16*)(ws + 0 * SZH);    // X-split / Vt hi+lo
  _Float16* b2 = (_Float16*)(ws + 2 * SZH);    // Qp hi+lo ; later wo-split
  _Float16* b3 = (_Float16*)(ws + 4 * SZH);    // Kp hi+lo
  char*     b4 = ws + 6 * SZH;                 // Vp f32 / O hi+lo

  _Float16* Xhi = b1;            _Float16* Xlo = b1 + NIN;
  _Float16* Qph = b2;            _Float16* Qpl = b2 + NIN;
  _Float16* Kph = b3;            _Float16* Kpl = b3 + NIN;
  float*    Vp  = (float*)b4;
  _Float16* Vth = (_Float16*)b1; _Float16* Vtl = (_Float16*)b1 + NIN;
  _Float16* Oh  = (_Float16*)b4; _Float16* Ol  = (_Float16*)b4 + NIN;
  _Float16* Wdh = (_Float16*)d_out; _Float16* Wdl = (_Float16*)d_out + NW;
  _Float16* Woh = (_Float16*)b2;    _Float16* Wol = (_Float16*)b2 + NW;

  const int NIN8 = (int)(NIN / 8), NW8 = (int)(NW / 8);
  dim3 gg(64, 8);

  // Q projection
  presplit<<<4096, 256, 0, stream>>>(q, Xhi, Xlo, NIN8);
  presplit<<<512, 256, 0, stream>>>(w_q, Wdh, Wdl, NW8);
  gemm_ps<0><<<gg, 256, 0, stream>>>(Xhi, Xlo, Wdh, Wdl, b_q, Qph, Qpl, nullptr);
  // K projection
  presplit<<<4096, 256, 0, stream>>>(k, Xhi, Xlo, NIN8);
  presplit<<<512, 256, 0, stream>>>(w_k, Wdh, Wdl, NW8);
  gemm_ps<0><<<gg, 256, 0, stream>>>(Xhi, Xlo, Wdh, Wdl, b_k, Kph, Kpl, nullptr);
  // V projection (fp32 out for transpose)
  presplit<<<4096, 256, 0, stream>>>(v, Xhi, Xlo, NIN8);
  presplit<<<512, 256, 0, stream>>>(w_v, Wdh, Wdl, NW8);
  gemm_ps<1><<<gg, 256, 0, stream>>>(Xhi, Xlo, Wdh, Wdl, b_v, nullptr, nullptr, Vp);
  // V transpose+split (b1's X-split dead)
  mha_vtrans<<<dim3(32, 64), 256, 0, stream>>>(Vp, Vth, Vtl);
  // attention: 512 blocks x 4 waves (Vp dead -> O into b4)
  mha_attn<<<dim3(8, 64), 256, 0, stream>>>(Qph, Qpl, Kph, Kpl, Vth, Vtl, Oh, Ol);
  // output projection (Qp dead -> w_o split into b2)
  presplit<<<512, 256, 0, stream>>>(w_o, Woh, Wol, NW8);
  gemm_ps<1><<<gg, 256, 0, stream>>>(Oh, Ol, Woh, Wol, b_o, nullptr, nullptr, (float*)d_out);
}